// Round 15
// baseline (520.550 us; speedup 1.0000x reference)
//
#include <hip/hip_runtime.h>
#include <hip/hip_bf16.h>

#define N 2048
#define NN (N * N)

typedef float f4 __attribute__((ext_vector_type(4)));
typedef float f2 __attribute__((ext_vector_type(2)));
typedef unsigned int u32;
typedef u32 u32x4 __attribute__((ext_vector_type(4)));

// ws float offsets (reduction scratch, < 1 MB total)
#define OFF_ROWSUM 0
#define OFF_COLSUM 32768
#define OFF_SUMS   65536      // [0..15]=diagsum, [16..31]=totsum
#define OFF_DIAG   65568
#define OFF_A      98336
#define OFF_B      131104
#define OFF_D      163872
#define OFF_C      196640
// pack area (u32 offsets within ws): XD at 1M u32 (4 MB), XT after XD
#define OFF_XD_U32 (1u << 20)
#define OFF_XT_U32 (OFF_XD_U32 + 4u * NN)
#define WS_NEEDED_BYTES ((size_t)(OFF_XT_U32 + 4u * NN) * 4)

// ---------------- fused pack(fp8) + reduce ----------------
// Block = (32-row slab s0, 64-col panel t0, channel-quad qz).
// Stages [4][32][68] f32 tile (nontemporal X loads -> keep L3 for packs);
// emits XD[qz][x][y] / XT[qz][t][s] as u32 of 4 fp8 e4m3 (one per channel).
// Pack total 134 MB, placed in d_ws (1 GiB): NO aliasing with out -> main
// reads it L3-warm with no interference from its own store stream.
__global__ __launch_bounds__(256, 4) void packreduce_kernel(const float* __restrict__ X,
                                                            float* __restrict__ ws,
                                                            u32* __restrict__ XD,
                                                            u32* __restrict__ XT) {
    const int s0 = blockIdx.x * 32;    // 64 slabs
    const int t0 = blockIdx.y * 64;    // 32 panels
    const int qz = blockIdx.z;         // 4 channel quads
    const int tid = threadIdx.x;

    __shared__ float lds[4][32][68];

    // stage: 4 ch x 32 rows x 16 f4
    #pragma unroll
    for (int j = 0; j < 8; ++j) {
        const int idx = tid + 256 * j;          // 0..2047
        const int ch = idx >> 9, row = (idx >> 4) & 31, q = idx & 15;
        const f4 v = __builtin_nontemporal_load(
            (const f4*)(X + (size_t)(4 * qz + ch) * NN + (size_t)(s0 + row) * N + t0 + 4 * q));
        *(f4*)&lds[ch][row][4 * q] = v;
    }
    __syncthreads();

    // XD: u32 = fp8(ch0..ch3) per pixel, direct layout
    #pragma unroll
    for (int j = 0; j < 2; ++j) {
        const int idx = tid + 256 * j;          // 0..511
        const int row = idx >> 4, c4 = idx & 15;
        u32x4 w;
        #pragma unroll
        for (int i = 0; i < 4; ++i) {
            const int c = 4 * c4 + i;
            int t = __builtin_amdgcn_cvt_pk_fp8_f32(lds[0][row][c], lds[1][row][c], 0, false);
            t = __builtin_amdgcn_cvt_pk_fp8_f32(lds[2][row][c], lds[3][row][c], t, true);
            w[i] = (u32)t;
        }
        *(u32x4*)(XD + (size_t)qz * NN + (size_t)(s0 + row) * N + t0 + 4 * c4) = w;
    }

    // XT: u32 = fp8(ch0..ch3) per pixel, transposed layout
    #pragma unroll
    for (int j = 0; j < 2; ++j) {
        const int idx = tid + 256 * j;          // 0..511
        const int tt = idx >> 3, sq = idx & 7;
        u32x4 w;
        #pragma unroll
        for (int i = 0; i < 4; ++i) {
            const int s = 4 * sq + i;
            int t = __builtin_amdgcn_cvt_pk_fp8_f32(lds[0][s][tt], lds[1][s][tt], 0, false);
            t = __builtin_amdgcn_cvt_pk_fp8_f32(lds[2][s][tt], lds[3][s][tt], t, true);
            w[i] = (u32)t;
        }
        *(u32x4*)(XT + (size_t)qz * NN + (size_t)(t0 + tt) * N + s0 + 4 * sq) = w;
    }

    // rowsum + diag (threads 0..127: ch = (tid>>5)&3, row = tid&31)
    if (tid < 128) {
        const int ch = (tid >> 5) & 3, row = tid & 31;
        const int c = 4 * qz + ch;
        float rs = 0.f;
        #pragma unroll
        for (int j = 0; j < 16; ++j) {
            const f4 v = *(const f4*)&lds[ch][row][4 * j];
            rs += (v.x + v.y) + (v.z + v.w);
        }
        atomicAdd(&ws[OFF_ROWSUM + c * N + s0 + row], rs);
        const int col = s0 + row - t0;
        if (col >= 0 && col < 64)
            ws[OFF_DIAG + c * N + s0 + row] = lds[ch][row][col];
    }

    // colsum (all 256: ch = tid>>6, col = tid&63)
    {
        const int ch = tid >> 6, col = tid & 63;
        float cs = 0.f;
        #pragma unroll
        for (int r = 0; r < 32; ++r) cs += lds[ch][r][col];
        atomicAdd(&ws[OFF_COLSUM + (4 * qz + ch) * N + t0 + col], cs);
    }
}

// ---------------- sums: diagsum / totsum per channel ----------------
__global__ __launch_bounds__(256) void sums_kernel(float* __restrict__ ws) {
    const int c = blockIdx.x;
    const int tid = threadIdx.x;
    float tot = 0.f, dg = 0.f;
    #pragma unroll
    for (int j = 0; j < 8; ++j) {
        tot += ws[OFF_ROWSUM + c * N + tid + 256 * j];
        dg  += ws[OFF_DIAG   + c * N + tid + 256 * j];
    }
    #pragma unroll
    for (int s = 1; s < 64; s <<= 1) { tot += __shfl_xor(tot, s); dg += __shfl_xor(dg, s); }
    __shared__ float buf[2][4];
    const int wave = tid >> 6, lane = tid & 63;
    if (lane == 0) { buf[0][wave] = tot; buf[1][wave] = dg; }
    __syncthreads();
    if (tid == 0) {
        ws[OFF_SUMS + 16 + c] = buf[0][0] + buf[0][1] + buf[0][2] + buf[0][3];
        ws[OFF_SUMS + c]      = buf[1][0] + buf[1][1] + buf[1][2] + buf[1][3];
    }
}

// ---------------- fold: A, B, D, C ----------------
__global__ __launch_bounds__(256) void fold_kernel(const float* __restrict__ W,
                                                   const float* __restrict__ bias,
                                                   float* __restrict__ ws) {
    const int o = blockIdx.y;
    const int x = blockIdx.x * 256 + threadIdx.x;
    const float invN = 1.f / (float)N;
    const float invN2 = invN * invN;
    const float* rowsum = ws + OFF_ROWSUM;
    const float* colsum = ws + OFF_COLSUM;
    const float* diagv  = ws + OFF_DIAG;
    const float* sums   = ws + OFF_SUMS;
    float* Abuf = ws + OFF_A;
    float* Bbuf = ws + OFF_B;
    float* Dbuf = ws + OFF_D;
    float* Cbuf = ws + OFF_C;

    if (blockIdx.x == 0 && threadIdx.x == 0) {
        float cacc = 0.f;
        #pragma unroll
        for (int c = 0; c < 16; ++c)
            cacc += (sums[c] * invN) * W[11 * 256 + c * 16 + o]
                  + (sums[16 + c] * invN2) * W[14 * 256 + c * 16 + o];
        float sb = 0.f;
        for (int p = 0; p < 15; ++p) sb += bias[p];
        Cbuf[o] = cacc + sb;
    }

    float du = 0.f;
    #pragma unroll
    for (int c = 0; c < 16; ++c)
        du += (sums[c] * invN) * W[2 * 256 + c * 16 + o]
            + (sums[16 + c] * invN2) * W[4 * 256 + c * 16 + o];

    float a = 0.f, b = 0.f, d = 0.f;
    #pragma unroll
    for (int c = 0; c < 16; ++c) {
        const float dg = diagv[c * N + x];
        const float rm = rowsum[c * N + x] * invN;
        const float cm = colsum[c * N + x] * invN;
        a += dg * W[5 * 256 + c * 16 + o] + rm * W[12 * 256 + c * 16 + o] + cm * W[7 * 256 + c * 16 + o];
        b += dg * W[9 * 256 + c * 16 + o] + rm * W[13 * 256 + c * 16 + o] + cm * W[10 * 256 + c * 16 + o];
        d += dg * W[0 * 256 + c * 16 + o] + rm * W[3 * 256 + c * 16 + o]  + cm * W[1 * 256 + c * 16 + o];
    }
    Abuf[o * N + x] = a;
    Bbuf[o * N + x] = b;
    Dbuf[o * N + x] = d + du;
}

// ---------------- main: fully-streaming, fp8 inputs ----------------
// 256 threads: og = tid>>7 (8 outputs), qi = tid&127 -> f4 pixel-quad.
// Reads XD+XT (fp8, 134 MB, in ws -> L3-resident, no aliasing with out),
// writes out f32 NONTEMPORAL. __syncthreads kept only for the out-alias
// fallback path (harmless otherwise).
__global__ __launch_bounds__(256, 4) void main_kernel(const float* __restrict__ W,
                                                      const float* __restrict__ ws,
                                                      const u32* __restrict__ XD,
                                                      const u32* __restrict__ XT,
                                                      float* __restrict__ out) {
    const int tid = threadIdx.x;
    const int og = __builtin_amdgcn_readfirstlane(tid >> 7);
    const int qi = tid & 127;
    const size_t p = ((size_t)blockIdx.x * 128 + qi) * 4;   // pixel flat index
    const int x = (int)(p >> 11);
    const int y = (int)(p & 2047);

    const float* Wid = W + 8 * 256 + og * 8;   // identity partition, o-slice
    const float* Wtr = W + 6 * 256 + og * 8;   // transpose partition, o-slice

    f4 acc[8];
    #pragma unroll
    for (int oo = 0; oo < 8; ++oo) acc[oo] = (f4)(0.f);

    #pragma unroll
    for (int qz = 0; qz < 4; ++qz) {
        const u32x4 xd = *(const u32x4*)(XD + (size_t)qz * NN + p);
        const u32x4 xt = *(const u32x4*)(XT + (size_t)qz * NN + p);
        f2 dlo[4], dhi[4], tlo[4], thi[4];
        #pragma unroll
        for (int i = 0; i < 4; ++i) {
            dlo[i] = __builtin_amdgcn_cvt_pk_f32_fp8((int)xd[i], false);
            dhi[i] = __builtin_amdgcn_cvt_pk_f32_fp8((int)xd[i], true);
            tlo[i] = __builtin_amdgcn_cvt_pk_f32_fp8((int)xt[i], false);
            thi[i] = __builtin_amdgcn_cvt_pk_f32_fp8((int)xt[i], true);
        }
        #pragma unroll
        for (int cq = 0; cq < 4; ++cq) {
            const int c = 4 * qz + cq;
            f4 xv, tv;
            #pragma unroll
            for (int i = 0; i < 4; ++i) {
                xv[i] = (cq == 0) ? dlo[i].x : (cq == 1) ? dlo[i].y : (cq == 2) ? dhi[i].x : dhi[i].y;
                tv[i] = (cq == 0) ? tlo[i].x : (cq == 1) ? tlo[i].y : (cq == 2) ? thi[i].x : thi[i].y;
            }
            const f4 wi0 = *(const f4*)&Wid[c * 16];
            const f4 wi1 = *(const f4*)&Wid[c * 16 + 4];
            const f4 wt0 = *(const f4*)&Wtr[c * 16];
            const f4 wt1 = *(const f4*)&Wtr[c * 16 + 4];
            #pragma unroll
            for (int oo = 0; oo < 4; ++oo) {
                acc[oo]     += wi0[oo] * xv + wt0[oo] * tv;
                acc[oo + 4] += wi1[oo] * xv + wt1[oo] * tv;
            }
        }
    }

    __syncthreads();   // ordering for the out-alias fallback only

    const float* Abuf = ws + OFF_A;
    const float* Bbuf = ws + OFF_B;
    const float* Dbuf = ws + OFF_D;
    const float* Cbuf = ws + OFF_C;

    #pragma unroll
    for (int oo = 0; oo < 8; ++oo) {
        const int o = og * 8 + oo;
        const float av = Abuf[o * N + x] + Cbuf[o];
        const f4 bv = *(const f4*)&Bbuf[o * N + y];
        f4 v = acc[oo] + av + bv;
        const int d = x - y;
        if (d >= 0 && d < 4) v[d] += Dbuf[o * N + x];
        __builtin_nontemporal_store(v, (f4*)(out + (size_t)o * NN + p));
    }
}

extern "C" void kernel_launch(void* const* d_in, const int* in_sizes, int n_in,
                              void* d_out, int out_size, void* d_ws, size_t ws_size,
                              hipStream_t stream) {
    (void)in_sizes; (void)n_in; (void)out_size;
    const float* X    = (const float*)d_in[0];
    const float* W    = (const float*)d_in[1];
    const float* bias = (const float*)d_in[2];
    float* out = (float*)d_out;
    float* ws  = (float*)d_ws;

    u32 *XD, *XT;
    if (ws_size >= WS_NEEDED_BYTES) {            // observed ws_size ~1 GiB
        XD = (u32*)ws + OFF_XD_U32;              // pack lives in scratch
        XT = (u32*)ws + OFF_XT_U32;
    } else {                                     // fallback: alias into out
        XD = (u32*)out;                          // (round-14 behavior, slower)
        XT = (u32*)out + (size_t)4 * NN;
    }

    (void)hipMemsetAsync(ws, 0, (OFF_SUMS + 32) * sizeof(float), stream);   // rowsum+colsum+sums
    packreduce_kernel<<<dim3(64, 32, 4), 256, 0, stream>>>(X, ws, XD, XT);
    sums_kernel<<<16, 256, 0, stream>>>(ws);
    fold_kernel<<<dim3(8, 16), 256, 0, stream>>>(W, bias, ws);
    main_kernel<<<8192, 256, 0, stream>>>(W, ws, XD, XT, out);
}

// Round 17
// 370.041 us; speedup vs baseline: 1.4067x; 1.4067x over previous
//
#include <hip/hip_runtime.h>
#include <hip/hip_bf16.h>

#define N 2048
#define NN (N * N)

typedef float f4 __attribute__((ext_vector_type(4)));
typedef float f2 __attribute__((ext_vector_type(2)));
typedef unsigned int u32;
typedef u32 u32x4 __attribute__((ext_vector_type(4)));

// ws float offsets (reduction scratch, < 1 MB total)
#define OFF_ROWSUM 0
#define OFF_COLSUM 32768
#define OFF_SUMS   65536      // [0..15]=diagsum, [16..31]=totsum
#define OFF_DIAG   65568
#define OFF_A      98336
#define OFF_B      131104
#define OFF_D      163872
#define OFF_C      196640
// pack area (u32 offsets within ws): XD at 1M u32 (4 MB), XT after XD
#define OFF_XD_U32 (1u << 20)
#define OFF_XT_U32 (OFF_XD_U32 + 4u * NN)
#define WS_NEEDED_BYTES ((size_t)(OFF_XT_U32 + 4u * NN) * 4)

// ---------------- fused pack(fp8) + reduce ----------------
// Block = (32-row slab s0, 64-col panel t0, channel-quad qz).
// Stages [4][32][68] f32 tile (nontemporal X loads); emits XD[qz][x][y] /
// XT[qz][t][s] as u32 of 4 fp8 e4m3 (one per channel) into d_ws, plus
// rowsum/colsum (sparse atomics) and diag.
__global__ __launch_bounds__(256, 4) void packreduce_kernel(const float* __restrict__ X,
                                                            float* __restrict__ ws,
                                                            u32* __restrict__ XD,
                                                            u32* __restrict__ XT) {
    const int s0 = blockIdx.x * 32;    // 64 slabs
    const int t0 = blockIdx.y * 64;    // 32 panels
    const int qz = blockIdx.z;         // 4 channel quads
    const int tid = threadIdx.x;

    __shared__ float lds[4][32][68];

    // stage: 4 ch x 32 rows x 16 f4
    #pragma unroll
    for (int j = 0; j < 8; ++j) {
        const int idx = tid + 256 * j;          // 0..2047
        const int ch = idx >> 9, row = (idx >> 4) & 31, q = idx & 15;
        const f4 v = __builtin_nontemporal_load(
            (const f4*)(X + (size_t)(4 * qz + ch) * NN + (size_t)(s0 + row) * N + t0 + 4 * q));
        *(f4*)&lds[ch][row][4 * q] = v;
    }
    __syncthreads();

    // XD: u32 = fp8(ch0..ch3) per pixel, direct layout
    #pragma unroll
    for (int j = 0; j < 2; ++j) {
        const int idx = tid + 256 * j;          // 0..511
        const int row = idx >> 4, c4 = idx & 15;
        u32x4 w;
        #pragma unroll
        for (int i = 0; i < 4; ++i) {
            const int c = 4 * c4 + i;
            int t = __builtin_amdgcn_cvt_pk_fp8_f32(lds[0][row][c], lds[1][row][c], 0, false);
            t = __builtin_amdgcn_cvt_pk_fp8_f32(lds[2][row][c], lds[3][row][c], t, true);
            w[i] = (u32)t;
        }
        *(u32x4*)(XD + (size_t)qz * NN + (size_t)(s0 + row) * N + t0 + 4 * c4) = w;
    }

    // XT: u32 = fp8(ch0..ch3) per pixel, transposed layout
    #pragma unroll
    for (int j = 0; j < 2; ++j) {
        const int idx = tid + 256 * j;          // 0..511
        const int tt = idx >> 3, sq = idx & 7;
        u32x4 w;
        #pragma unroll
        for (int i = 0; i < 4; ++i) {
            const int s = 4 * sq + i;
            int t = __builtin_amdgcn_cvt_pk_fp8_f32(lds[0][s][tt], lds[1][s][tt], 0, false);
            t = __builtin_amdgcn_cvt_pk_fp8_f32(lds[2][s][tt], lds[3][s][tt], t, true);
            w[i] = (u32)t;
        }
        *(u32x4*)(XT + (size_t)qz * NN + (size_t)(t0 + tt) * N + s0 + 4 * sq) = w;
    }

    // rowsum + diag (threads 0..127: ch = (tid>>5)&3, row = tid&31)
    if (tid < 128) {
        const int ch = (tid >> 5) & 3, row = tid & 31;
        const int c = 4 * qz + ch;
        float rs = 0.f;
        #pragma unroll
        for (int j = 0; j < 16; ++j) {
            const f4 v = *(const f4*)&lds[ch][row][4 * j];
            rs += (v.x + v.y) + (v.z + v.w);
        }
        atomicAdd(&ws[OFF_ROWSUM + c * N + s0 + row], rs);
        const int col = s0 + row - t0;
        if (col >= 0 && col < 64)
            ws[OFF_DIAG + c * N + s0 + row] = lds[ch][row][col];
    }

    // colsum (all 256: ch = tid>>6, col = tid&63)
    {
        const int ch = tid >> 6, col = tid & 63;
        float cs = 0.f;
        #pragma unroll
        for (int r = 0; r < 32; ++r) cs += lds[ch][r][col];
        atomicAdd(&ws[OFF_COLSUM + (4 * qz + ch) * N + t0 + col], cs);
    }
}

// ---------------- sums: diagsum / totsum per channel ----------------
__global__ __launch_bounds__(256) void sums_kernel(float* __restrict__ ws) {
    const int c = blockIdx.x;
    const int tid = threadIdx.x;
    float tot = 0.f, dg = 0.f;
    #pragma unroll
    for (int j = 0; j < 8; ++j) {
        tot += ws[OFF_ROWSUM + c * N + tid + 256 * j];
        dg  += ws[OFF_DIAG   + c * N + tid + 256 * j];
    }
    #pragma unroll
    for (int s = 1; s < 64; s <<= 1) { tot += __shfl_xor(tot, s); dg += __shfl_xor(dg, s); }
    __shared__ float buf[2][4];
    const int wave = tid >> 6, lane = tid & 63;
    if (lane == 0) { buf[0][wave] = tot; buf[1][wave] = dg; }
    __syncthreads();
    if (tid == 0) {
        ws[OFF_SUMS + 16 + c] = buf[0][0] + buf[0][1] + buf[0][2] + buf[0][3];
        ws[OFF_SUMS + c]      = buf[1][0] + buf[1][1] + buf[1][2] + buf[1][3];
    }
}

// ---------------- fold: A, B, D, C ----------------
__global__ __launch_bounds__(256) void fold_kernel(const float* __restrict__ W,
                                                   const float* __restrict__ bias,
                                                   float* __restrict__ ws) {
    const int o = blockIdx.y;
    const int x = blockIdx.x * 256 + threadIdx.x;
    const float invN = 1.f / (float)N;
    const float invN2 = invN * invN;
    const float* rowsum = ws + OFF_ROWSUM;
    const float* colsum = ws + OFF_COLSUM;
    const float* diagv  = ws + OFF_DIAG;
    const float* sums   = ws + OFF_SUMS;
    float* Abuf = ws + OFF_A;
    float* Bbuf = ws + OFF_B;
    float* Dbuf = ws + OFF_D;
    float* Cbuf = ws + OFF_C;

    if (blockIdx.x == 0 && threadIdx.x == 0) {
        float cacc = 0.f;
        #pragma unroll
        for (int c = 0; c < 16; ++c)
            cacc += (sums[c] * invN) * W[11 * 256 + c * 16 + o]
                  + (sums[16 + c] * invN2) * W[14 * 256 + c * 16 + o];
        float sb = 0.f;
        for (int p = 0; p < 15; ++p) sb += bias[p];
        Cbuf[o] = cacc + sb;
    }

    float du = 0.f;
    #pragma unroll
    for (int c = 0; c < 16; ++c)
        du += (sums[c] * invN) * W[2 * 256 + c * 16 + o]
            + (sums[16 + c] * invN2) * W[4 * 256 + c * 16 + o];

    float a = 0.f, b = 0.f, d = 0.f;
    #pragma unroll
    for (int c = 0; c < 16; ++c) {
        const float dg = diagv[c * N + x];
        const float rm = rowsum[c * N + x] * invN;
        const float cm = colsum[c * N + x] * invN;
        a += dg * W[5 * 256 + c * 16 + o] + rm * W[12 * 256 + c * 16 + o] + cm * W[7 * 256 + c * 16 + o];
        b += dg * W[9 * 256 + c * 16 + o] + rm * W[13 * 256 + c * 16 + o] + cm * W[10 * 256 + c * 16 + o];
        d += dg * W[0 * 256 + c * 16 + o] + rm * W[3 * 256 + c * 16 + o]  + cm * W[1 * 256 + c * 16 + o];
    }
    Abuf[o * N + x] = a;
    Bbuf[o * N + x] = b;
    Dbuf[o * N + x] = d + du;
}

// ---------------- main: fully-streaming, fp8 inputs, spill-free unpack ----------------
// Channel-PAIR unpack at point of use (template<bool HI> since the builtin's
// word arg must be a front-end constant). One f2 pair live at a time ->
// live set ~56 VGPR, same as the proven bf16 kernel.
template <bool HI>
__device__ __forceinline__ void fma_half(const u32x4& xd, const u32x4& xt,
                                         const float* Wid, const float* Wtr,
                                         int c0, f4* acc) {
    const f4 wiA = *(const f4*)&Wid[c0 * 16];
    const f4 wiB = *(const f4*)&Wid[c0 * 16 + 4];
    const f4 wiC = *(const f4*)&Wid[c0 * 16 + 16];
    const f4 wiD = *(const f4*)&Wid[c0 * 16 + 20];
    const f4 wtA = *(const f4*)&Wtr[c0 * 16];
    const f4 wtB = *(const f4*)&Wtr[c0 * 16 + 4];
    const f4 wtC = *(const f4*)&Wtr[c0 * 16 + 16];
    const f4 wtD = *(const f4*)&Wtr[c0 * 16 + 20];
    #pragma unroll
    for (int i = 0; i < 4; ++i) {
        const f2 d = __builtin_amdgcn_cvt_pk_f32_fp8((int)xd[i], HI);
        const f2 t = __builtin_amdgcn_cvt_pk_f32_fp8((int)xt[i], HI);
        #pragma unroll
        for (int oo = 0; oo < 4; ++oo) {
            acc[oo][i]     += wiA[oo] * d.x + wiC[oo] * d.y + wtA[oo] * t.x + wtC[oo] * t.y;
            acc[oo + 4][i] += wiB[oo] * d.x + wiD[oo] * d.y + wtB[oo] * t.x + wtD[oo] * t.y;
        }
    }
}

__global__ __launch_bounds__(256, 4) void main_kernel(const float* __restrict__ W,
                                                      const float* __restrict__ ws,
                                                      const u32* __restrict__ XD,
                                                      const u32* __restrict__ XT,
                                                      float* __restrict__ out) {
    const int tid = threadIdx.x;
    const int og = __builtin_amdgcn_readfirstlane(tid >> 7);
    const int qi = tid & 127;
    const size_t p = ((size_t)blockIdx.x * 128 + qi) * 4;   // pixel flat index
    const int x = (int)(p >> 11);
    const int y = (int)(p & 2047);

    const float* Wid = W + 8 * 256 + og * 8;   // identity partition, o-slice
    const float* Wtr = W + 6 * 256 + og * 8;   // transpose partition, o-slice

    f4 acc[8];
    #pragma unroll
    for (int oo = 0; oo < 8; ++oo) acc[oo] = (f4)(0.f);

    #pragma unroll
    for (int qz = 0; qz < 4; ++qz) {
        const u32x4 xd = *(const u32x4*)(XD + (size_t)qz * NN + p);
        const u32x4 xt = *(const u32x4*)(XT + (size_t)qz * NN + p);
        fma_half<false>(xd, xt, Wid, Wtr, 4 * qz,     acc);
        fma_half<true >(xd, xt, Wid, Wtr, 4 * qz + 2, acc);
    }

    __syncthreads();   // ordering for the out-alias fallback only

    const float* Abuf = ws + OFF_A;
    const float* Bbuf = ws + OFF_B;
    const float* Dbuf = ws + OFF_D;
    const float* Cbuf = ws + OFF_C;

    #pragma unroll
    for (int oo = 0; oo < 8; ++oo) {
        const int o = og * 8 + oo;
        const float av = Abuf[o * N + x] + Cbuf[o];
        const f4 bv = *(const f4*)&Bbuf[o * N + y];
        f4 v = acc[oo] + av + bv;
        const int d = x - y;
        if (d >= 0 && d < 4) v[d] += Dbuf[o * N + x];
        __builtin_nontemporal_store(v, (f4*)(out + (size_t)o * NN + p));
    }
}

extern "C" void kernel_launch(void* const* d_in, const int* in_sizes, int n_in,
                              void* d_out, int out_size, void* d_ws, size_t ws_size,
                              hipStream_t stream) {
    (void)in_sizes; (void)n_in; (void)out_size;
    const float* X    = (const float*)d_in[0];
    const float* W    = (const float*)d_in[1];
    const float* bias = (const float*)d_in[2];
    float* out = (float*)d_out;
    float* ws  = (float*)d_ws;

    u32 *XD, *XT;
    if (ws_size >= WS_NEEDED_BYTES) {            // observed ws_size ~1 GiB
        XD = (u32*)ws + OFF_XD_U32;              // pack lives in scratch
        XT = (u32*)ws + OFF_XT_U32;
    } else {                                     // fallback: alias into out
        XD = (u32*)out;
        XT = (u32*)out + (size_t)4 * NN;
    }

    (void)hipMemsetAsync(ws, 0, (OFF_SUMS + 32) * sizeof(float), stream);   // rowsum+colsum+sums
    packreduce_kernel<<<dim3(64, 32, 4), 256, 0, stream>>>(X, ws, XD, XT);
    sums_kernel<<<16, 256, 0, stream>>>(ws);
    fold_kernel<<<dim3(8, 16), 256, 0, stream>>>(W, bias, ws);
    main_kernel<<<8192, 256, 0, stream>>>(W, ws, XD, XT, out);
}